// Round 2
// baseline (97.065 us; speedup 1.0000x reference)
//
#include <hip/hip_runtime.h>
#include <stdint.h>

#define NB 8
#define NR 4096
#define NG 512
#define OUTG 35
#define PER_B (NG*OUTG + NR*2)   // 17920 + 8192 = 26112
#define GT_BLOCKS 512            // 4 waves/block x 2 GT/wave x 512 = 4096 GTs
#define FP_BLOCKS 128            // 16 blocks/batch x 8 batches

__constant__ int   c_GROUP[10] = {0,1,1,2,2,3,4,4,5,5};
__constant__ float c_HIGH[10]  = {2.0f,2.5f,2.5f,3.5f,2.5f,0.5f,1.0f,1.0f,0.5f,0.5f};
__constant__ float c_MED[10]   = {4.0f,4.0f,4.0f,4.0f,4.0f,2.5f,2.5f,2.5f,2.0f,2.0f};

// largest x such that sqrtf(x) <= t. t*t is exact for all thresholds used
// (2.0, 2.5, 3.5, 0.5, 1.0, 4.0 -> squares have <=6 significand bits), so
// (d <= t with d = sqrtf(d2))  <=>  (d2 <= B(t)) bit-exactly for IEEE sqrt.
__device__ __forceinline__ float sqrt_le_bound(float t) {
  float B = t * t;
  while (sqrtf(__uint_as_float(__float_as_uint(B) + 1u)) <= t)
    B = __uint_as_float(__float_as_uint(B) + 1u);
  return B;
}

// ---------------------------------------------------------------------------
// Prep: pack per-ROI {x,y,score,group(or -1 if invalid)} and per-GT {x,y}
// (invalid GT -> coords 1e30 so d^2 overflows to +inf, matching
//  jnp.where(valid_gt, d, inf) in the fp reduction).
// ---------------------------------------------------------------------------
__global__ __launch_bounds__(256) void prep_kernel(
    const float* __restrict__ rois,
    const float* __restrict__ scores,
    const float* __restrict__ gt,
    const int*   __restrict__ labels,
    float4* __restrict__ ws_roi,
    float4* __restrict__ ws_gt) {
  int tid = blockIdx.x * 256 + threadIdx.x;
  if (tid < NB * NR) {
    const float* rr = rois + (size_t)tid * 9;
    float s = rr[0];
    #pragma unroll
    for (int k = 1; k < 9; ++k) s += rr[k];
    bool valid = (s != 0.0f);
    int lab = labels[tid];
    lab = min(max(lab, 0), 9);
    float w = valid ? (float)c_GROUP[lab] : -1.0f;
    ws_roi[tid] = make_float4(rr[0], rr[1], scores[tid], w);
  } else if (tid < NB * NR + NB * NG) {
    int i = tid - NB * NR;
    const float* gr = gt + (size_t)i * 10;
    float s = gr[0];
    #pragma unroll
    for (int k = 1; k < 10; ++k) s += gr[k];
    bool valid = (s != 0.0f);
    ws_gt[i] = make_float4(valid ? gr[0] : 1e30f, valid ? gr[1] : 1e30f, 0.f, 0.f);
  }
}

// Write one GT's 35 output floats from the reduced high/med keys.
__device__ __forceinline__ void write_gt_row(
    float* __restrict__ og, const float gv[10], bool gvalid,
    unsigned long long uh, unsigned long long um,
    const float* __restrict__ rois_b) {
  bool has_high = (uh != 0ull);
  bool has_med  = (um != 0ull);
  bool sel_med  = (!has_high) && has_med;
  bool matched  = has_high || has_med;
  int   hi  = NR - 1 - (int)(unsigned int)(uh & 0xffffffffull);
  int   mi  = NR - 1 - (int)(unsigned int)(um & 0xffffffffull);
  float hsc = __uint_as_float((unsigned int)(uh >> 32) - 1u);
  float msc = __uint_as_float((unsigned int)(um >> 32) - 1u);
  const float* hr = rois_b + (size_t)(has_high ? hi : 0) * 9;
  const float* mr = rois_b + (size_t)(sel_med ? mi : 0) * 9;
  #pragma unroll
  for (int k = 0; k < 9; ++k) og[k] = has_high ? hr[k] : 0.0f;
  og[9]  = has_high ? fminf((1.2f + hsc) * 0.5f, 1.0f) : 0.0f;
  og[10] = has_high ? 1.0f : 0.0f;
  #pragma unroll
  for (int k = 0; k < 9; ++k) og[11 + k] = sel_med ? mr[k] : 0.0f;
  og[20] = sel_med ? msc : 0.0f;
  og[21] = sel_med ? 1.0f : 0.0f;
  #pragma unroll
  for (int k = 0; k < 10; ++k) og[22 + k] = matched ? gv[k] : 0.0f;
  bool unmatched = gvalid && !has_high && !has_med;
  float rng  = sqrtf(__fmul_rn(gv[0], gv[0]) + __fmul_rn(gv[1], gv[1]));
  bool nearb = unmatched && (rng < 30.0f);
  bool farb  = unmatched && (rng > 50.0f);
  bool midb  = unmatched && !nearb && !farb;
  og[32] = nearb ? 1.0f : 0.0f;
  og[33] = midb  ? 1.0f : 0.0f;
  og[34] = farb  ? 1.0f : 0.0f;
}

// ---------------------------------------------------------------------------
// Fused: blocks [0,GT_BLOCKS) do GT matching (one wave = 2 GTs, 64 lanes
// scan 4096 packed ROIs); blocks [GT_BLOCKS, +FP_BLOCKS) do the per-ROI
// false-positive test (one thread per ROI, GTs staged in LDS).
// ---------------------------------------------------------------------------
__global__ __launch_bounds__(256) void main_kernel(
    const float* __restrict__ rois,
    const float* __restrict__ gt,
    const float4* __restrict__ ws_roi,
    const float4* __restrict__ ws_gt,
    float* __restrict__ out) {
  __shared__ float2 sgt[NG];

  if (blockIdx.x < GT_BLOCKS) {
    // ---------------- GT matching ----------------
    int wave = threadIdx.x >> 6;
    int lane = threadIdx.x & 63;
    int widx = blockIdx.x * 4 + wave;      // global wave id, 0..2047
    int idx0 = widx * 2;                   // first GT index (b*NG+g)
    int b    = idx0 >> 9;

    float gv0[10], gv1[10];
    {
      const float* g0 = gt + (size_t)idx0 * 10;
      #pragma unroll
      for (int k = 0; k < 10; ++k) gv0[k] = g0[k];
      #pragma unroll
      for (int k = 0; k < 10; ++k) gv1[k] = g0[10 + k];
    }
    float s0 = gv0[0], s1 = gv1[0];
    #pragma unroll
    for (int k = 1; k < 10; ++k) { s0 += gv0[k]; s1 += gv1[k]; }
    bool gvalid0 = (s0 != 0.0f), gvalid1 = (s1 != 0.0f);

    int cls0 = min(max((int)gv0[9], 0), 9);
    int cls1 = min(max((int)gv1[9], 0), 9);
    float Bh0 = sqrt_le_bound(c_HIGH[cls0]);
    float Bm0 = sqrt_le_bound(c_MED[cls0]);
    float Bh1 = sqrt_le_bound(c_HIGH[cls1]);
    float Bm1 = sqrt_le_bound(c_MED[cls1]);
    float gw0 = gvalid0 ? (float)c_GROUP[cls0] : -2.0f;  // -2 matches nothing
    float gw1 = gvalid1 ? (float)c_GROUP[cls1] : -2.0f;
    float gx0 = gv0[0], gy0 = gv0[1];
    float gx1 = gv1[0], gy1 = gv1[1];

    const float4* rp = ws_roi + (size_t)b * NR;
    unsigned long long uh0 = 0ull, um0 = 0ull, uh1 = 0ull, um1 = 0ull;
    #pragma unroll 4
    for (int r = lane; r < NR; r += 64) {
      float4 p = rp[r];
      unsigned long long key =
          ((unsigned long long)(__float_as_uint(p.z) + 1u) << 32) |
          (unsigned int)(NR - 1 - r);
      {
        float dx = p.x - gx0, dy = p.y - gy0;
        float d2 = __fmul_rn(dx, dx) + __fmul_rn(dy, dy);  // mul,mul,add as ref
        bool mm = (p.w == gw0) && (d2 <= Bm0);
        bool hh = mm && (d2 <= Bh0);
        bool ee = mm && !(d2 <= Bh0);
        if (hh && key > uh0) uh0 = key;
        if (ee && key > um0) um0 = key;
      }
      {
        float dx = p.x - gx1, dy = p.y - gy1;
        float d2 = __fmul_rn(dx, dx) + __fmul_rn(dy, dy);
        bool mm = (p.w == gw1) && (d2 <= Bm1);
        bool hh = mm && (d2 <= Bh1);
        bool ee = mm && !(d2 <= Bh1);
        if (hh && key > uh1) uh1 = key;
        if (ee && key > um1) um1 = key;
      }
    }
    #pragma unroll
    for (int off = 32; off > 0; off >>= 1) {
      unsigned long long t;
      t = __shfl_xor(uh0, off, 64); if (t > uh0) uh0 = t;
      t = __shfl_xor(um0, off, 64); if (t > um0) um0 = t;
      t = __shfl_xor(uh1, off, 64); if (t > uh1) uh1 = t;
      t = __shfl_xor(um1, off, 64); if (t > um1) um1 = t;
    }

    const float* rois_b = rois + (size_t)b * NR * 9;
    float* outb = out + (size_t)b * PER_B;
    if (lane == 0) {
      write_gt_row(outb + (size_t)(idx0 & 511) * OUTG, gv0, gvalid0, uh0, um0, rois_b);
    } else if (lane == 1) {
      write_gt_row(outb + (size_t)((idx0 + 1) & 511) * OUTG, gv1, gvalid1, uh1, um1, rois_b);
    }
  } else {
    // ---------------- false-positive ROIs ----------------
    int fb = blockIdx.x - GT_BLOCKS;               // 0..127
    int b  = fb >> 4;                              // 16 blocks per batch
    int r  = ((fb & 15) << 8) + threadIdx.x;

    const float4* gp = ws_gt + (size_t)b * NG;
    for (int j = threadIdx.x; j < NG; j += 256) {
      float4 v = gp[j];
      sgt[j] = make_float2(v.x, v.y);
    }
    __syncthreads();

    float4 p = ws_roi[(size_t)b * NR + r];
    float m2 = __builtin_inff();
    #pragma unroll 8
    for (int j = 0; j < NG; ++j) {
      float2 q = sgt[j];
      float dx = p.x - q.x, dy = p.y - q.y;
      float d2 = __fmul_rn(dx, dx) + __fmul_rn(dy, dy);
      m2 = fminf(m2, d2);
    }
    // min(sqrt(x)) == sqrt(min(x)) for monotone correctly-rounded sqrt
    bool fp = (p.w >= 0.0f) && (sqrtf(m2) > 4.0f);
    float* orow = out + (size_t)b * PER_B + NG * OUTG + (size_t)r * 2;
    orow[0] = fp ? p.z : 0.0f;
    orow[1] = fp ? 1.0f : 0.0f;
  }
}

// ---------------------------------------------------------------------------
extern "C" void kernel_launch(void* const* d_in, const int* in_sizes, int n_in,
                              void* d_out, int out_size, void* d_ws, size_t ws_size,
                              hipStream_t stream) {
  const float* rois   = (const float*)d_in[0];
  const float* scores = (const float*)d_in[1];
  const float* gt     = (const float*)d_in[2];
  const int*   labels = (const int*)d_in[3];
  float* out = (float*)d_out;

  float4* ws_roi = (float4*)d_ws;                 // NB*NR float4 = 512 KiB
  float4* ws_gt  = ws_roi + (size_t)NB * NR;      // NB*NG float4 =  64 KiB

  int total = NB * NR + NB * NG;                  // 36864 prep items
  prep_kernel<<<(total + 255) / 256, 256, 0, stream>>>(rois, scores, gt, labels,
                                                       ws_roi, ws_gt);
  main_kernel<<<GT_BLOCKS + FP_BLOCKS, 256, 0, stream>>>(rois, gt, ws_roi, ws_gt, out);
}

// Round 3
// 92.677 us; speedup vs baseline: 1.0473x; 1.0473x over previous
//
#include <hip/hip_runtime.h>
#include <stdint.h>

#define NB 8
#define NR 4096
#define NG 512
#define OUTG 35
#define PER_B (NG*OUTG + NR*2)   // 17920 + 8192 = 26112

__constant__ int   c_GROUP[10] = {0,1,1,2,2,3,4,4,5,5};
__constant__ float c_HIGH[10]  = {2.0f,2.5f,2.5f,3.5f,2.5f,0.5f,1.0f,1.0f,0.5f,0.5f};
__constant__ float c_MED[10]   = {4.0f,4.0f,4.0f,4.0f,4.0f,2.5f,2.5f,2.5f,2.0f,2.0f};

// largest x such that sqrtf(x) <= t (self-calibrating against the actual
// sqrtf, so (sqrtf(d2) <= t) <=> (d2 <= B(t)) bit-exactly; sqrtf monotone).
__device__ __forceinline__ float sqrt_le_bound(float t) {
  float B = t * t;
  while (sqrtf(__uint_as_float(__float_as_uint(B) + 1u)) <= t)
    B = __uint_as_float(__float_as_uint(B) + 1u);
  return B;
}

// Write one GT's 35 output floats from the reduced high/med keys.
__device__ __forceinline__ void write_gt_row(
    float* __restrict__ og, const float gv[10], bool gvalid,
    unsigned long long uh, unsigned long long um,
    const float* __restrict__ rois_b) {
  bool has_high = (uh != 0ull);
  bool has_med  = (um != 0ull);
  bool sel_med  = (!has_high) && has_med;
  bool matched  = has_high || has_med;
  int   hi  = NR - 1 - (int)(unsigned int)(uh & 0xffffffffull);
  int   mi  = NR - 1 - (int)(unsigned int)(um & 0xffffffffull);
  float hsc = __uint_as_float((unsigned int)(uh >> 32) - 1u);
  float msc = __uint_as_float((unsigned int)(um >> 32) - 1u);
  const float* hr = rois_b + (size_t)(has_high ? hi : 0) * 9;
  const float* mr = rois_b + (size_t)(sel_med ? mi : 0) * 9;
  #pragma unroll
  for (int k = 0; k < 9; ++k) og[k] = has_high ? hr[k] : 0.0f;
  og[9]  = has_high ? fminf((1.2f + hsc) * 0.5f, 1.0f) : 0.0f;
  og[10] = has_high ? 1.0f : 0.0f;
  #pragma unroll
  for (int k = 0; k < 9; ++k) og[11 + k] = sel_med ? mr[k] : 0.0f;
  og[20] = sel_med ? msc : 0.0f;
  og[21] = sel_med ? 1.0f : 0.0f;
  #pragma unroll
  for (int k = 0; k < 10; ++k) og[22 + k] = matched ? gv[k] : 0.0f;
  bool unmatched = gvalid && !has_high && !has_med;
  float rng  = sqrtf(__fmul_rn(gv[0], gv[0]) + __fmul_rn(gv[1], gv[1]));
  bool nearb = unmatched && (rng < 30.0f);
  bool farb  = unmatched && (rng > 50.0f);
  bool midb  = unmatched && !nearb && !farb;
  og[32] = nearb ? 1.0f : 0.0f;
  og[33] = midb  ? 1.0f : 0.0f;
  og[34] = farb  ? 1.0f : 0.0f;
}

// ---------------------------------------------------------------------------
// Single fused kernel. Grid = 256 blocks x 512 threads; 32 blocks per batch.
// Each block: stage batch ROIs (64KB) + GT xy (4KB) in LDS; then
//   - match: 8 waves x 2 GTs, 64 lanes scan 4096 LDS ROIs, u64-key argmax;
//   - fp: this block's 128-ROI slice, 4 lanes per ROI (quarter GT range each).
// No workspace usage at all (d_ws untouched).
// ---------------------------------------------------------------------------
__global__ __launch_bounds__(512) void fused_kernel(
    const float* __restrict__ rois,
    const float* __restrict__ scores,
    const float* __restrict__ gt,
    const int*   __restrict__ labels,
    float* __restrict__ out) {
  __shared__ float4 sroi[NR];   // 64 KB: {x, y, score, group or -1}
  __shared__ float2 sgt[NG];    //  4 KB: {x, y} (invalid -> 1e30)

  int tid = threadIdx.x;
  int bid = blockIdx.x;
  int b   = bid >> 5;           // 32 blocks per batch
  int sub = bid & 31;

  const float* rois_b = rois   + (size_t)b * NR * 9;
  const float* sc_b   = scores + (size_t)b * NR;
  const int*   lab_b  = labels + (size_t)b * NR;
  const float* gt_b   = gt     + (size_t)b * NG * 10;

  // ---- stage ROIs: 8 rows per thread
  #pragma unroll 4
  for (int k = 0; k < 8; ++k) {
    int r = tid + k * 512;
    const float* rr = rois_b + (size_t)r * 9;
    float s = rr[0];
    #pragma unroll
    for (int j = 1; j < 9; ++j) s += rr[j];     // sequential, matches ref
    bool valid = (s != 0.0f);
    int lab = min(max(lab_b[r], 0), 9);
    float w = valid ? (float)c_GROUP[lab] : -1.0f;
    sroi[r] = make_float4(rr[0], rr[1], sc_b[r], w);
  }
  // ---- stage GT xy (one per thread; 512 threads = 512 GTs)
  {
    const float* gr = gt_b + (size_t)tid * 10;
    float s = gr[0];
    #pragma unroll
    for (int j = 1; j < 10; ++j) s += gr[j];
    bool valid = (s != 0.0f);
    sgt[tid] = make_float2(valid ? gr[0] : 1e30f, valid ? gr[1] : 1e30f);
  }
  __syncthreads();

  // ================= match phase =================
  int wave = tid >> 6;
  int lane = tid & 63;
  int g0   = sub * 16 + wave * 2;               // in-batch GT index (and g0+1)

  float gv0[10], gv1[10];
  {
    const float* gp = gt_b + (size_t)g0 * 10;   // wave-uniform address
    #pragma unroll
    for (int k = 0; k < 10; ++k) gv0[k] = gp[k];
    #pragma unroll
    for (int k = 0; k < 10; ++k) gv1[k] = gp[10 + k];
  }
  float s0 = gv0[0], s1 = gv1[0];
  #pragma unroll
  for (int k = 1; k < 10; ++k) { s0 += gv0[k]; s1 += gv1[k]; }
  bool gvalid0 = (s0 != 0.0f), gvalid1 = (s1 != 0.0f);

  int cls0 = min(max((int)gv0[9], 0), 9);
  int cls1 = min(max((int)gv1[9], 0), 9);
  float Bh0 = sqrt_le_bound(c_HIGH[cls0]);
  float Bm0 = sqrt_le_bound(c_MED[cls0]);
  float Bh1 = sqrt_le_bound(c_HIGH[cls1]);
  float Bm1 = sqrt_le_bound(c_MED[cls1]);
  float gw0 = gvalid0 ? (float)c_GROUP[cls0] : -2.0f;  // -2 matches nothing
  float gw1 = gvalid1 ? (float)c_GROUP[cls1] : -2.0f;
  float gx0 = gv0[0], gy0 = gv0[1];
  float gx1 = gv1[0], gy1 = gv1[1];

  unsigned long long uh0 = 0ull, um0 = 0ull, uh1 = 0ull, um1 = 0ull;
  #pragma unroll 4
  for (int r = lane; r < NR; r += 64) {
    float4 p = sroi[r];
    unsigned long long key =
        ((unsigned long long)(__float_as_uint(p.z) + 1u) << 32) |
        (unsigned int)(NR - 1 - r);
    {
      float dx = p.x - gx0, dy = p.y - gy0;
      float d2 = __fmul_rn(dx, dx) + __fmul_rn(dy, dy);  // mul,mul,add as ref
      bool mm = (p.w == gw0) && (d2 <= Bm0);
      bool hh = mm && (d2 <= Bh0);
      bool ee = mm && !(d2 <= Bh0);
      if (hh && key > uh0) uh0 = key;
      if (ee && key > um0) um0 = key;
    }
    {
      float dx = p.x - gx1, dy = p.y - gy1;
      float d2 = __fmul_rn(dx, dx) + __fmul_rn(dy, dy);
      bool mm = (p.w == gw1) && (d2 <= Bm1);
      bool hh = mm && (d2 <= Bh1);
      bool ee = mm && !(d2 <= Bh1);
      if (hh && key > uh1) uh1 = key;
      if (ee && key > um1) um1 = key;
    }
  }
  #pragma unroll
  for (int off = 32; off > 0; off >>= 1) {
    unsigned long long t;
    t = __shfl_xor(uh0, off, 64); if (t > uh0) uh0 = t;
    t = __shfl_xor(um0, off, 64); if (t > um0) um0 = t;
    t = __shfl_xor(uh1, off, 64); if (t > uh1) uh1 = t;
    t = __shfl_xor(um1, off, 64); if (t > um1) um1 = t;
  }

  float* outb = out + (size_t)b * PER_B;
  if (lane == 0) {
    write_gt_row(outb + (size_t)g0 * OUTG, gv0, gvalid0, uh0, um0, rois_b);
  } else if (lane == 1) {
    write_gt_row(outb + (size_t)(g0 + 1) * OUTG, gv1, gvalid1, uh1, um1, rois_b);
  }

  // ================= fp phase =================
  // This block's slice: 128 ROIs; lanes (rl,q): q covers GT quarter q*128..+128
  {
    int rl = tid >> 2;                 // 0..127
    int q  = tid & 3;
    int r  = sub * 128 + rl;           // in-batch ROI index
    float4 p = sroi[r];
    float m2 = __builtin_inff();
    #pragma unroll 4
    for (int jj = 0; jj < 128; ++jj) {
      int j = q * 128 + ((jj + q * 4) & 127);    // stagger: bank-conflict-free
      float2 qq = sgt[j];
      float dx = p.x - qq.x, dy = p.y - qq.y;
      float d2 = __fmul_rn(dx, dx) + __fmul_rn(dy, dy);
      m2 = fminf(m2, d2);
    }
    float t;
    t = __shfl_xor(m2, 1, 64); m2 = fminf(m2, t);
    t = __shfl_xor(m2, 2, 64); m2 = fminf(m2, t);
    if (q == 0) {
      // min(sqrt(x)) == sqrt(min(x)) for monotone sqrtf
      bool fp = (p.w >= 0.0f) && (sqrtf(m2) > 4.0f);
      float* orow = out + (size_t)b * PER_B + NG * OUTG + (size_t)r * 2;
      orow[0] = fp ? p.z : 0.0f;
      orow[1] = fp ? 1.0f : 0.0f;
    }
  }
}

// ---------------------------------------------------------------------------
extern "C" void kernel_launch(void* const* d_in, const int* in_sizes, int n_in,
                              void* d_out, int out_size, void* d_ws, size_t ws_size,
                              hipStream_t stream) {
  const float* rois   = (const float*)d_in[0];
  const float* scores = (const float*)d_in[1];
  const float* gt     = (const float*)d_in[2];
  const int*   labels = (const int*)d_in[3];
  float* out = (float*)d_out;
  (void)d_ws; (void)ws_size;   // deliberately unused

  fused_kernel<<<NB * 32, 512, 0, stream>>>(rois, scores, gt, labels, out);
}

// Round 4
// 80.257 us; speedup vs baseline: 1.2094x; 1.1548x over previous
//
#include <hip/hip_runtime.h>
#include <stdint.h>

#define NB 8
#define NR 4096
#define NG 512
#define OUTG 35
#define PER_B (NG*OUTG + NR*2)   // 17920 + 8192 = 26112

__constant__ int   c_GROUP[10] = {0,1,1,2,2,3,4,4,5,5};
__constant__ float c_HIGH[10]  = {2.0f,2.5f,2.5f,3.5f,2.5f,0.5f,1.0f,1.0f,0.5f,0.5f};
__constant__ float c_MED[10]   = {4.0f,4.0f,4.0f,4.0f,4.0f,2.5f,2.5f,2.5f,2.0f,2.0f};

// largest x such that sqrtf(x) <= t (self-calibrating against the actual
// sqrtf; sqrtf monotone => (sqrtf(d2) <= t) <=> (d2 <= B(t)) bit-exactly).
__device__ __forceinline__ float sqrt_le_bound(float t) {
  float B = t * t;
  while (sqrtf(__uint_as_float(__float_as_uint(B) + 1u)) <= t)
    B = __uint_as_float(__float_as_uint(B) + 1u);
  return B;
}

// Single-key emit: key = (is_high<<44) | (scorebits+1)<<12 | (4095-r).
// Max over keys gives: best-high if any high match exists, else best-med,
// with first-index tie-break (larger 4095-r = smaller r), exactly matching
// the reference's two argmax's + selection logic.
__device__ __forceinline__ void write_gt_row(
    float* __restrict__ og, const float gv[10], bool gvalid,
    unsigned long long key, const float* __restrict__ rois_b) {
  bool has_match = (key != 0ull);
  bool has_high  = (key >> 44) != 0ull;
  bool sel_med   = has_match && !has_high;
  int   idx = NR - 1 - (int)(key & 0xFFFull);
  float sc  = __uint_as_float((unsigned int)((key >> 12) & 0xFFFFFFFFull) - 1u);
  const float* wr = rois_b + (size_t)(has_match ? idx : 0) * 9;
  #pragma unroll
  for (int k = 0; k < 9; ++k) og[k] = has_high ? wr[k] : 0.0f;
  og[9]  = has_high ? fminf((1.2f + sc) * 0.5f, 1.0f) : 0.0f;
  og[10] = has_high ? 1.0f : 0.0f;
  #pragma unroll
  for (int k = 0; k < 9; ++k) og[11 + k] = sel_med ? wr[k] : 0.0f;
  og[20] = sel_med ? sc : 0.0f;
  og[21] = sel_med ? 1.0f : 0.0f;
  #pragma unroll
  for (int k = 0; k < 10; ++k) og[22 + k] = has_match ? gv[k] : 0.0f;
  bool unmatched = gvalid && !has_match;
  float rng  = sqrtf(__fmul_rn(gv[0], gv[0]) + __fmul_rn(gv[1], gv[1]));
  bool nearb = unmatched && (rng < 30.0f);
  bool farb  = unmatched && (rng > 50.0f);
  bool midb  = unmatched && !nearb && !farb;
  og[32] = nearb ? 1.0f : 0.0f;
  og[33] = midb  ? 1.0f : 0.0f;
  og[34] = farb  ? 1.0f : 0.0f;
}

// ---------------------------------------------------------------------------
// 256 blocks x 512 threads; 32 blocks per batch. Stage batch ROIs (64KB) +
// GT xy (4KB) in LDS, then wave role-split:
//   waves 0-3: match — 4 GTs/wave, 64 lanes scan 4096 LDS ROIs, u64-key max
//   waves 4-7: fp    — block's 128-ROI slice, 2 lanes/ROI, float4 GT pairs
// One match + one fp wave per SIMD overlap on separate data. d_ws unused.
// ---------------------------------------------------------------------------
__global__ __launch_bounds__(512) void fused_kernel(
    const float* __restrict__ rois,
    const float* __restrict__ scores,
    const float* __restrict__ gt,
    const int*   __restrict__ labels,
    float* __restrict__ out) {
  __shared__ float4 sroi[NR];                    // 64 KB {x,y,score,group|-1}
  __shared__ __align__(16) float2 sgt[NG];       //  4 KB {x,y} (invalid->1e30)

  int tid = threadIdx.x;
  int bid = blockIdx.x;
  int b   = bid >> 5;
  int sub = bid & 31;

  const float* rois_b = rois   + (size_t)b * NR * 9;
  const float* sc_b   = scores + (size_t)b * NR;
  const int*   lab_b  = labels + (size_t)b * NR;
  const float* gt_b   = gt     + (size_t)b * NG * 10;

  // ---- stage ROIs: 8 rows per thread (bit-exact sequential validity sum)
  #pragma unroll 4
  for (int k = 0; k < 8; ++k) {
    int r = tid + k * 512;
    const float* rr = rois_b + (size_t)r * 9;
    float s = rr[0];
    #pragma unroll
    for (int j = 1; j < 9; ++j) s += rr[j];
    bool valid = (s != 0.0f);
    int lab = min(max(lab_b[r], 0), 9);
    float w = valid ? (float)c_GROUP[lab] : -1.0f;
    sroi[r] = make_float4(rr[0], rr[1], sc_b[r], w);
  }
  // ---- stage GT xy
  {
    const float* gr = gt_b + (size_t)tid * 10;
    float s = gr[0];
    #pragma unroll
    for (int j = 1; j < 10; ++j) s += gr[j];
    bool valid = (s != 0.0f);
    sgt[tid] = make_float2(valid ? gr[0] : 1e30f, valid ? gr[1] : 1e30f);
  }
  __syncthreads();

  if (tid < 256) {
    // ================= match: 4 waves x 4 GTs =================
    int wave = tid >> 6;
    int lane = tid & 63;
    int g0   = sub * 16 + wave * 4;

    float gx[4], gy[4], gw[4], Bh[4], Bm[4];
    {
      const float* gp = gt_b + (size_t)g0 * 10;  // wave-uniform
      #pragma unroll
      for (int i = 0; i < 4; ++i) {
        float gv[10];
        #pragma unroll
        for (int k = 0; k < 10; ++k) gv[k] = gp[i * 10 + k];
        float s = gv[0];
        #pragma unroll
        for (int k = 1; k < 10; ++k) s += gv[k];
        bool gvalid = (s != 0.0f);
        int cls = min(max((int)gv[9], 0), 9);
        gx[i] = gv[0];
        gy[i] = gv[1];
        Bh[i] = sqrt_le_bound(c_HIGH[cls]);
        Bm[i] = sqrt_le_bound(c_MED[cls]);
        gw[i] = gvalid ? (float)c_GROUP[cls] : -2.0f;  // -2 matches nothing
      }
    }

    unsigned long long best0 = 0ull, best1 = 0ull, best2 = 0ull, best3 = 0ull;
    #pragma unroll 4
    for (int r = lane; r < NR; r += 64) {
      float4 p = sroi[r];
      unsigned int sc1 = __float_as_uint(p.z) + 1u;      // < 2^30
      unsigned long long base =
          ((unsigned long long)sc1 << 12) | (unsigned int)(NR - 1 - r);
      {
        float dx = p.x - gx[0], dy = p.y - gy[0];
        float d2 = __fmul_rn(dx, dx) + __fmul_rn(dy, dy);
        bool mm = (p.w == gw[0]) && (d2 <= Bm[0]);
        unsigned long long key = base | ((d2 <= Bh[0]) ? (1ull << 44) : 0ull);
        if (mm && key > best0) best0 = key;
      }
      {
        float dx = p.x - gx[1], dy = p.y - gy[1];
        float d2 = __fmul_rn(dx, dx) + __fmul_rn(dy, dy);
        bool mm = (p.w == gw[1]) && (d2 <= Bm[1]);
        unsigned long long key = base | ((d2 <= Bh[1]) ? (1ull << 44) : 0ull);
        if (mm && key > best1) best1 = key;
      }
      {
        float dx = p.x - gx[2], dy = p.y - gy[2];
        float d2 = __fmul_rn(dx, dx) + __fmul_rn(dy, dy);
        bool mm = (p.w == gw[2]) && (d2 <= Bm[2]);
        unsigned long long key = base | ((d2 <= Bh[2]) ? (1ull << 44) : 0ull);
        if (mm && key > best2) best2 = key;
      }
      {
        float dx = p.x - gx[3], dy = p.y - gy[3];
        float d2 = __fmul_rn(dx, dx) + __fmul_rn(dy, dy);
        bool mm = (p.w == gw[3]) && (d2 <= Bm[3]);
        unsigned long long key = base | ((d2 <= Bh[3]) ? (1ull << 44) : 0ull);
        if (mm && key > best3) best3 = key;
      }
    }
    #pragma unroll
    for (int off = 32; off > 0; off >>= 1) {
      unsigned long long t;
      t = __shfl_xor(best0, off, 64); if (t > best0) best0 = t;
      t = __shfl_xor(best1, off, 64); if (t > best1) best1 = t;
      t = __shfl_xor(best2, off, 64); if (t > best2) best2 = t;
      t = __shfl_xor(best3, off, 64); if (t > best3) best3 = t;
    }

    if (lane < 4) {
      unsigned long long key = (lane == 0) ? best0
                             : (lane == 1) ? best1
                             : (lane == 2) ? best2 : best3;
      int g = g0 + lane;
      const float* gr = gt_b + (size_t)g * 10;
      float gv[10];
      #pragma unroll
      for (int k = 0; k < 10; ++k) gv[k] = gr[k];
      float s = gv[0];
      #pragma unroll
      for (int k = 1; k < 10; ++k) s += gv[k];
      bool gvalid = (s != 0.0f);
      float* og = out + (size_t)b * PER_B + (size_t)g * OUTG;
      write_gt_row(og, gv, gvalid, key, rois_b);
    }
  } else {
    // ================= fp: 4 waves, 2 lanes per ROI =================
    int t  = tid - 256;                  // 0..255
    int rl = t >> 1;                     // 0..127
    int q  = t & 1;                      // GT half
    int r  = sub * 128 + rl;
    float4 p = sroi[r];
    float B4 = sqrt_le_bound(4.0f);
    const float4* sgt4 = (const float4*)sgt;     // 2 GTs per read
    int fnd = 0;
    #pragma unroll 4
    for (int j = 0; j < 128; ++j) {
      float4 v = sgt4[q * 128 + j];
      float dxa = p.x - v.x, dya = p.y - v.y;
      float d2a = __fmul_rn(dxa, dxa) + __fmul_rn(dya, dya);
      float dxb = p.x - v.z, dyb = p.y - v.w;
      float d2b = __fmul_rn(dxb, dxb) + __fmul_rn(dyb, dyb);
      fnd |= (int)(d2a <= B4) | (int)(d2b <= B4);
    }
    fnd |= __shfl_xor(fnd, 1, 64);
    if (q == 0) {
      // dmin > 4.0  <=>  no valid GT with d2 <= B4 (sqrtf monotone)
      bool fp = (p.w >= 0.0f) && !fnd;
      float* orow = out + (size_t)b * PER_B + NG * OUTG + (size_t)r * 2;
      orow[0] = fp ? p.z : 0.0f;
      orow[1] = fp ? 1.0f : 0.0f;
    }
  }
}

// ---------------------------------------------------------------------------
extern "C" void kernel_launch(void* const* d_in, const int* in_sizes, int n_in,
                              void* d_out, int out_size, void* d_ws, size_t ws_size,
                              hipStream_t stream) {
  const float* rois   = (const float*)d_in[0];
  const float* scores = (const float*)d_in[1];
  const float* gt     = (const float*)d_in[2];
  const int*   labels = (const int*)d_in[3];
  float* out = (float*)d_out;
  (void)d_ws; (void)ws_size;   // deliberately unused

  fused_kernel<<<NB * 32, 512, 0, stream>>>(rois, scores, gt, labels, out);
}